// Round 7
// baseline (329.211 us; speedup 1.0000x reference)
//
#include <hip/hip_runtime.h>
#include <hip/hip_bf16.h>
#include <math.h>

#define BETA 0.125f
#define INV_BETA 8.0f

typedef __attribute__((ext_vector_type(8))) short short8v;
typedef __attribute__((ext_vector_type(4))) float f32x4;
typedef union { short8v v; unsigned short u[8]; } v8u;

// ws layout (float units)
#define OFF_XB   0u          // bf16 x      [4096][1024]
#define OFF_WCB  2097152u    // bf16 Wcat   [2048][1024]
#define OFF_WCTB 3145728u    // bf16 WcatT  [1024][2048]
#define OFF_WHB  4194304u    // bf16 Whop   [1024][4096]
#define OFF_WHTB 6291456u    // bf16 WhopT  [4096][1024]
#define OFF_H    8388608u    // bf16 H      [4096][4096]
#define OFF_QB   16777216u   // bf16 Qb     [64][1024][64]
#define OFF_KB   18874368u   // bf16 Kb
#define OFF_QT   20971520u   // bf16 QT     [64][64][1024]
#define OFF_KT   23068672u   // bf16 KT
#define OFF_DQK  25165824u   // bf16 dQKcat [4096][2048]
#define OFF_LSE  29360128u   // f32 [65536]
#define OFF_PL   29425664u   // f32 [2048]
#define OFF_PH   29427712u   // f32 [1024]

__device__ __forceinline__ unsigned short f2b(float f) {
    unsigned u = __float_as_uint(f);
    return (unsigned short)((u + 0x7fffu + ((u >> 16) & 1u)) >> 16);
}

__device__ __forceinline__ void gload_lds16(const unsigned short* g, void* l) {
    __builtin_amdgcn_global_load_lds(
        (const __attribute__((address_space(1))) unsigned int*)g,
        (__attribute__((address_space(3))) unsigned int*)l, 16, 0, 0);
}

// ---------------- fused bf16 cast of all 4 inputs ----------------
// float4-unit ranges: x [0,1048576) Wq [1048576,1310720) Wk [1310720,1572864) Whop [1572864,2621440)
__global__ __launch_bounds__(256) void k_castall(const float* __restrict__ x,
                                                 const float* __restrict__ Wq,
                                                 const float* __restrict__ Wk,
                                                 const float* __restrict__ Whop,
                                                 unsigned short* __restrict__ XB,
                                                 unsigned short* __restrict__ WCB,
                                                 unsigned short* __restrict__ WHB) {
    int i = blockIdx.x * 256 + threadIdx.x;
    const float* s;
    unsigned short* d;
    int j;
    if (i < 1048576) { s = x; d = XB; j = i; }
    else if (i < 1310720) { s = Wq; d = WCB; j = i - 1048576; }
    else if (i < 1572864) { s = Wk; d = WCB + 1048576; j = i - 1310720; }
    else { s = Whop; d = WHB; j = i - 1572864; }
    float4 v = ((const float4*)s)[j];
    ushort4 o;
    o.x = f2b(v.x); o.y = f2b(v.y); o.z = f2b(v.z); o.w = f2b(v.w);
    ((ushort4*)d)[j] = o;
}

// ---------------- fused bf16 transposes (x<64: WcatT, else WhopT) ----------------
__global__ void k_tall(const float* __restrict__ Wq, const float* __restrict__ Wk,
                       const float* __restrict__ Whop,
                       unsigned short* __restrict__ WCTB, unsigned short* __restrict__ WHTB) {
    __shared__ float t[32][33];
    int bx = blockIdx.x;
    int tx = threadIdx.x, ty = threadIdx.y;
    if (bx < 64) {
        int j0 = bx * 32, d0 = blockIdx.y * 32;
#pragma unroll
        for (int i = 0; i < 4; ++i) {
            int j = j0 + ty + 8 * i;
            const float* src = (j < 1024) ? (Wq + (size_t)j * 1024) : (Wk + (size_t)(j - 1024) * 1024);
            t[ty + 8 * i][tx] = src[d0 + tx];
        }
        __syncthreads();
#pragma unroll
        for (int i = 0; i < 4; ++i)
            WCTB[(size_t)(d0 + ty + 8 * i) * 2048 + j0 + tx] = f2b(t[tx][ty + 8 * i]);
    } else {
        int e0 = (bx - 64) * 32, d0 = blockIdx.y * 32;
#pragma unroll
        for (int i = 0; i < 4; ++i)
            t[ty + 8 * i][tx] = Whop[(size_t)(d0 + ty + 8 * i) * 4096 + e0 + tx];
        __syncthreads();
#pragma unroll
        for (int i = 0; i < 4; ++i)
            WHTB[(size_t)(e0 + ty + 8 * i) * 1024 + d0 + tx] = f2b(t[tx][ty + 8 * i]);
    }
}

// ============ m97-structure GEMM cores (NT: A[M][K] x B[N][K]) ============
// single-buffer variant (used by hopfwd: grid 4/CU, dbuf would cut occupancy - m132)
template <int NJ>
__device__ __forceinline__ void gemm_core(const unsigned short* __restrict__ A, int lda,
                                          const unsigned short* __restrict__ Bm, int ldb,
                                          int kdim, int rowBase, int colBase,
                                          unsigned short* ldsA, unsigned short* ldsB,
                                          f32x4 (&acc)[4][NJ]) {
    const int tid = threadIdx.x, lane = tid & 63;
    const int wv = tid >> 6;
    const int lr = lane & 15, lg = lane >> 4;
    const int wrow = (wv >> 1) * 64;
    const int wcol = (wv & 1) * (NJ * 16);

    for (int kk = 0; kk < kdim; kk += 64) {
#pragma unroll
        for (int iss = 0; iss < 4; ++iss) {
            int p = iss * 256 + tid;
            int row = p >> 3, c = p & 7, cs = c ^ (row & 7);
            gload_lds16(&A[(size_t)(rowBase + row) * lda + kk + cs * 8], (char*)ldsA + p * 16);
        }
#pragma unroll
        for (int iss = 0; iss < NJ; ++iss) {
            int p = iss * 256 + tid;
            int row = p >> 3, c = p & 7, cs = c ^ (row & 7);
            gload_lds16(&Bm[(size_t)(colBase + row) * ldb + kk + cs * 8], (char*)ldsB + p * 16);
        }
        __syncthreads();
#pragma unroll
        for (int kc = 0; kc < 2; ++kc) {
            short8v av[4], bv[NJ];
#pragma unroll
            for (int i = 0; i < 4; ++i) {
                int row = wrow + i * 16 + lr;
                int phys = row * 128 + ((kc * 4 + lg) ^ (row & 7)) * 16;
                av[i] = *(const short8v*)((const char*)ldsA + phys);
            }
#pragma unroll
            for (int j = 0; j < NJ; ++j) {
                int row = wcol + j * 16 + lr;
                int phys = row * 128 + ((kc * 4 + lg) ^ (row & 7)) * 16;
                bv[j] = *(const short8v*)((const char*)ldsB + phys);
            }
#pragma unroll
            for (int i = 0; i < 4; ++i)
#pragma unroll
                for (int j = 0; j < NJ; ++j)
                    acc[i][j] = __builtin_amdgcn_mfma_f32_16x16x32_bf16(av[i], bv[j], acc[i][j], 0, 0, 0);
        }
        __syncthreads();
    }
}

// 2-phase double-buffered variant (T3 minimum recipe): issue STAGE(t+1) before compute(t),
// one barrier (with its vmcnt drain) per K-step.
template <int NJ>
__device__ __forceinline__ void gemm_core_db(const unsigned short* __restrict__ A, int lda,
                                             const unsigned short* __restrict__ Bm, int ldb,
                                             int kdim, int rowBase, int colBase,
                                             unsigned short (*ldsA)[128 * 64],
                                             unsigned short (*ldsB)[NJ * 32 * 64],
                                             f32x4 (&acc)[4][NJ]) {
    const int tid = threadIdx.x, lane = tid & 63;
    const int wv = tid >> 6;
    const int lr = lane & 15, lg = lane >> 4;
    const int wrow = (wv >> 1) * 64;
    const int wcol = (wv & 1) * (NJ * 16);

    auto stage = [&](int buf, int kk) {
#pragma unroll
        for (int iss = 0; iss < 4; ++iss) {
            int p = iss * 256 + tid;
            int row = p >> 3, c = p & 7, cs = c ^ (row & 7);
            gload_lds16(&A[(size_t)(rowBase + row) * lda + kk + cs * 8], (char*)&ldsA[buf][0] + p * 16);
        }
#pragma unroll
        for (int iss = 0; iss < NJ; ++iss) {
            int p = iss * 256 + tid;
            int row = p >> 3, c = p & 7, cs = c ^ (row & 7);
            gload_lds16(&Bm[(size_t)(colBase + row) * ldb + kk + cs * 8], (char*)&ldsB[buf][0] + p * 16);
        }
    };

    stage(0, 0);
    __syncthreads();
    int buf = 0;
    for (int kk = 0; kk < kdim; kk += 64) {
        if (kk + 64 < kdim) stage(buf ^ 1, kk + 64);
        const char* La = (const char*)&ldsA[buf][0];
        const char* Lb = (const char*)&ldsB[buf][0];
#pragma unroll
        for (int kc = 0; kc < 2; ++kc) {
            short8v av[4], bv[NJ];
#pragma unroll
            for (int i = 0; i < 4; ++i) {
                int row = wrow + i * 16 + lr;
                av[i] = *(const short8v*)(La + row * 128 + ((kc * 4 + lg) ^ (row & 7)) * 16);
            }
#pragma unroll
            for (int j = 0; j < NJ; ++j) {
                int row = wcol + j * 16 + lr;
                bv[j] = *(const short8v*)(Lb + row * 128 + ((kc * 4 + lg) ^ (row & 7)) * 16);
            }
#pragma unroll
            for (int i = 0; i < 4; ++i)
#pragma unroll
                for (int j = 0; j < NJ; ++j)
                    acc[i][j] = __builtin_amdgcn_mfma_f32_16x16x32_bf16(av[i], bv[j], acc[i][j], 0, 0, 0);
        }
        __syncthreads();
        buf ^= 1;
    }
}

#define GEMM_IDX(NJ)                                                             \
    const int tid = threadIdx.x, lane = tid & 63, wv = tid >> 6;                 \
    const int lr = lane & 15, lg = lane >> 4;                                    \
    const int row0 = blockIdx.x * 128 + (wv >> 1) * 64;                          \
    const int col0 = blockIdx.y * (NJ * 32) + (wv & 1) * (NJ * 16);              \
    f32x4 acc[4][NJ];                                                            \
    _Pragma("unroll") for (int i = 0; i < 4; ++i)                                \
        _Pragma("unroll") for (int j = 0; j < NJ; ++j)                           \
            acc[i][j] = (f32x4){0.f, 0.f, 0.f, 0.f};

// ---------------- K1: Q/K projection (BN=128, dbuf: grid-limited 2/CU) ----------------
__global__ __launch_bounds__(256) void mm_proj(const unsigned short* __restrict__ XB,
                                               const unsigned short* __restrict__ WCB,
                                               unsigned short* __restrict__ Qb,
                                               unsigned short* __restrict__ Kb) {
    __shared__ unsigned short ldsA[2][128 * 64];
    __shared__ unsigned short ldsB[2][128 * 64];
    GEMM_IDX(4)
    gemm_core_db<4>(XB, 1024, WCB, 1024, 1024, blockIdx.x * 128, blockIdx.y * 128, ldsA, ldsB, acc);
    unsigned short* dst = (col0 < 1024) ? Qb : Kb;
    const int cbase = col0 & 1023;
#pragma unroll
    for (int i = 0; i < 4; ++i)
#pragma unroll
        for (int r = 0; r < 4; ++r) {
            int rg = row0 + i * 16 + lg * 4 + r;
            int bb = rg >> 10, n = rg & 1023;
#pragma unroll
            for (int j = 0; j < 4; ++j) {
                int c = cbase + j * 16 + lr;
                int h = c >> 6, q = c & 63;
                dst[((size_t)(bb * 16 + h) * 1024 + n) * 64 + q] = f2b(acc[i][j][r]);
            }
        }
}

// ---------------- K6: H = relu(x Whop) (BN=128, single-buffer) ----------------
__global__ __launch_bounds__(256) void mm_hopfwd(const unsigned short* __restrict__ XB,
                                                 const unsigned short* __restrict__ WHTB,
                                                 unsigned short* __restrict__ H,
                                                 float* __restrict__ PH) {
    __shared__ unsigned short ldsA[128 * 64];
    __shared__ unsigned short ldsB[128 * 64];
    __shared__ float red[4];
    GEMM_IDX(4)
    gemm_core<4>(XB, 1024, WHTB, 1024, 1024, blockIdx.x * 128, blockIdx.y * 128, ldsA, ldsB, acc);
    float ss = 0.f;
#pragma unroll
    for (int i = 0; i < 4; ++i)
#pragma unroll
        for (int r = 0; r < 4; ++r) {
            size_t rg = row0 + i * 16 + lg * 4 + r;
#pragma unroll
            for (int j = 0; j < 4; ++j) {
                float hv = fmaxf(acc[i][j][r], 0.f);
                ss += hv * hv;
                H[rg * 4096 + col0 + j * 16 + lr] = f2b(hv);
            }
        }
#pragma unroll
    for (int off = 32; off; off >>= 1) ss += __shfl_down(ss, off);
    if (lane == 0) red[wv] = ss;
    __syncthreads();
    if (tid == 0) PH[blockIdx.y * gridDim.x + blockIdx.x] = red[0] + red[1] + red[2] + red[3];
}

// ---------------- K7: out = -(H Whop^T) (BN=64, dbuf 48KB -> 3/CU) ----------------
__global__ __launch_bounds__(256) void mm_hopbwd(const unsigned short* __restrict__ H,
                                                 const unsigned short* __restrict__ WHB,
                                                 float* __restrict__ out) {
    __shared__ unsigned short ldsA[2][128 * 64];
    __shared__ unsigned short ldsB[2][64 * 64];
    GEMM_IDX(2)
    gemm_core_db<2>(H, 4096, WHB, 4096, 4096, blockIdx.x * 128, blockIdx.y * 64, ldsA, ldsB, acc);
#pragma unroll
    for (int i = 0; i < 4; ++i)
#pragma unroll
        for (int r = 0; r < 4; ++r) {
            size_t rg = row0 + i * 16 + lg * 4 + r;
#pragma unroll
            for (int j = 0; j < 2; ++j)
                out[rg * 1024 + col0 + j * 16 + lr] = -acc[i][j][r];
        }
}

// ---------------- K5: out += dQKcat WcatT (BN=64, dbuf) ----------------
__global__ __launch_bounds__(256) void mm_gradproj(const unsigned short* __restrict__ DQK,
                                                   const unsigned short* __restrict__ WCTB,
                                                   float* __restrict__ out) {
    __shared__ unsigned short ldsA[2][128 * 64];
    __shared__ unsigned short ldsB[2][64 * 64];
    GEMM_IDX(2)
    gemm_core_db<2>(DQK, 2048, WCTB, 2048, 2048, blockIdx.x * 128, blockIdx.y * 64, ldsA, ldsB, acc);
#pragma unroll
    for (int i = 0; i < 4; ++i)
#pragma unroll
        for (int r = 0; r < 4; ++r) {
            size_t rg = row0 + i * 16 + lg * 4 + r;
#pragma unroll
            for (int j = 0; j < 2; ++j) {
                size_t idx = rg * 1024 + col0 + j * 16 + lr;
                out[idx] += acc[i][j][r];
            }
        }
}

// ---------------- transpose Qb/Kb -> QT/KT ----------------
__global__ __launch_bounds__(256) void k_tqk(const unsigned short* __restrict__ Qb,
                                             const unsigned short* __restrict__ Kb,
                                             unsigned short* __restrict__ QT,
                                             unsigned short* __restrict__ KT) {
    __shared__ unsigned short T[64][65];
    const int z = blockIdx.z;
    const unsigned short* src = z ? Kb : Qb;
    unsigned short* dst = z ? KT : QT;
    const int bh = blockIdx.y;
    const int n0 = blockIdx.x * 64;
    const int t = threadIdx.x;
    {
        int row = t >> 3;
        int colc = (t & 7) * 8;
#pragma unroll
        for (int ii = 0; ii < 2; ++ii) {
            int r = row + 32 * ii;
            v8u vv;
            vv.v = *(const short8v*)&src[((size_t)(bh << 10) + n0 + r) * 64 + colc];
#pragma unroll
            for (int j = 0; j < 8; ++j) T[r][colc + j] = vv.u[j];
        }
    }
    __syncthreads();
    {
        int q = t >> 2;
        int nc = (t & 3) * 16;
        unsigned short buf[16];
#pragma unroll
        for (int j = 0; j < 16; ++j) buf[j] = T[nc + j][q];
        *(short8v*)&dst[((size_t)bh * 64 + q) * 1024 + n0 + nc] = *(short8v*)&buf[0];
        *(short8v*)&dst[((size_t)bh * 64 + q) * 1024 + n0 + nc + 8] = *(short8v*)&buf[8];
    }
}

// ---------------- K3: fused lse + dQ (staged, 2-phase) ----------------
__global__ __launch_bounds__(256) void k_dq(const unsigned short* __restrict__ Qb,
                                            const unsigned short* __restrict__ Kb,
                                            const unsigned short* __restrict__ KT,
                                            float* __restrict__ LSE,
                                            float* __restrict__ PL,
                                            unsigned short* __restrict__ DQK) {
    __shared__ unsigned short Ktile[2][64 * 64];
    __shared__ unsigned short Ttile[2][64 * 64];
    __shared__ unsigned short P[4][2048];
    const int tid = threadIdx.x, lane = tid & 63, wv = tid >> 6;
    const int bh = blockIdx.x, nt = blockIdx.y;
    const int nw = nt * 128 + wv * 32;
    const int lr = lane & 15, lg = lane >> 4;
    unsigned short* Pw = &P[wv][0];

    auto stage = [&](int buf, int m0) {
#pragma unroll
        for (int iss = 0; iss < 2; ++iss) {
            int p = iss * 256 + tid;
            int row = p >> 3, c = p & 7, cs = c ^ (row & 7);
            gload_lds16(&Kb[((size_t)(bh << 10) + m0 + row) * 64 + cs * 8],
                        (char*)&Ktile[buf][0] + p * 16);
            gload_lds16(&KT[((size_t)bh * 64 + row) * 1024 + m0 + cs * 8],
                        (char*)&Ttile[buf][0] + p * 16);
        }
    };

    short8v qa[2][2];
#pragma unroll
    for (int rb = 0; rb < 2; ++rb)
#pragma unroll
        for (int kc = 0; kc < 2; ++kc)
            qa[rb][kc] = *(const short8v*)&Qb[((size_t)(bh << 10) + nw + rb * 16 + lr) * 64 + kc * 32 + lg * 8];

    float sm[2][4];
    f32x4 dq[2][4];
#pragma unroll
    for (int rb = 0; rb < 2; ++rb) {
#pragma unroll
        for (int r = 0; r < 4; ++r) sm[rb][r] = 0.f;
#pragma unroll
        for (int qb = 0; qb < 4; ++qb) dq[rb][qb] = (f32x4){0.f, 0.f, 0.f, 0.f};
    }

    stage(0, 0);
    __syncthreads();
    int buf = 0;
    for (int mt = 0; mt < 16; ++mt) {
        if (mt < 15) stage(buf ^ 1, (mt + 1) * 64);
        const char* Kt = (const char*)&Ktile[buf][0];
        const char* Tt = (const char*)&Ttile[buf][0];
#pragma unroll
        for (int ct = 0; ct < 4; ++ct) {
            int brow = ct * 16 + lr;
            short8v bk0 = *(const short8v*)(Kt + brow * 128 + ((lg) ^ (brow & 7)) * 16);
            short8v bk1 = *(const short8v*)(Kt + brow * 128 + ((lg + 4) ^ (brow & 7)) * 16);
#pragma unroll
            for (int rb = 0; rb < 2; ++rb) {
                f32x4 s = {0.f, 0.f, 0.f, 0.f};
                s = __builtin_amdgcn_mfma_f32_16x16x32_bf16(qa[rb][0], bk0, s, 0, 0, 0);
                s = __builtin_amdgcn_mfma_f32_16x16x32_bf16(qa[rb][1], bk1, s, 0, 0, 0);
#pragma unroll
                for (int r = 0; r < 4; ++r) {
                    float p = __expf(s[r] * BETA);
                    sm[rb][r] += p;
                    int row = rb * 16 + lg * 4 + r;
                    int off = (row * 64 + ct * 16 + lr) ^ ((row & 7) << 3);
                    Pw[off] = f2b(p);
                }
            }
        }
        short8v pa[2][2];
#pragma unroll
        for (int rb = 0; rb < 2; ++rb) {
            int row = rb * 16 + lr;
#pragma unroll
            for (int kc = 0; kc < 2; ++kc) {
                int off = (row * 64 + kc * 32 + lg * 8) ^ ((row & 7) << 3);
                pa[rb][kc] = *(const short8v*)&Pw[off];
            }
        }
#pragma unroll
        for (int qb = 0; qb < 4; ++qb) {
            int brow = qb * 16 + lr;
            short8v b0 = *(const short8v*)(Tt + brow * 128 + ((lg) ^ (brow & 7)) * 16);
            short8v b1 = *(const short8v*)(Tt + brow * 128 + ((lg + 4) ^ (brow & 7)) * 16);
#pragma unroll
            for (int rb = 0; rb < 2; ++rb) {
                dq[rb][qb] = __builtin_amdgcn_mfma_f32_16x16x32_bf16(pa[rb][0], b0, dq[rb][qb], 0, 0, 0);
                dq[rb][qb] = __builtin_amdgcn_mfma_f32_16x16x32_bf16(pa[rb][1], b1, dq[rb][qb], 0, 0, 0);
            }
        }
        __syncthreads();
        buf ^= 1;
    }

#pragma unroll
    for (int off = 1; off < 16; off <<= 1)
#pragma unroll
        for (int rb = 0; rb < 2; ++rb)
#pragma unroll
            for (int r = 0; r < 4; ++r) sm[rb][r] += __shfl_xor(sm[rb][r], off);

    const int b = bh >> 4, h = bh & 15;
#pragma unroll
    for (int rb = 0; rb < 2; ++rb) {
#pragma unroll
        for (int r = 0; r < 4; ++r) {
            float inv = 1.0f / sm[rb][r];
#pragma unroll
            for (int qb = 0; qb < 4; ++qb)
                DQK[((size_t)(b << 10) + nw + rb * 16 + lg * 4 + r) * 2048 + h * 64 + qb * 16 + lr] =
                    f2b(-dq[rb][qb][r] * inv);
        }
    }

    float lsum = 0.f;
    if (lr == 0) {
#pragma unroll
        for (int rb = 0; rb < 2; ++rb)
#pragma unroll
            for (int r = 0; r < 4; ++r) {
                float l = __logf(sm[rb][r]);
                LSE[(size_t)(bh << 10) + nw + rb * 16 + lg * 4 + r] = l;
                lsum += l;
            }
    }
    lsum += __shfl_xor(lsum, 16);
    lsum += __shfl_xor(lsum, 32);
    if (lane == 0) PL[(size_t)(bh * 8 + nt) * 4 + wv] = lsum;
}

// ---------------- K4: dK = -P^T Q (staged, 2-phase) ----------------
__global__ __launch_bounds__(256) void k_dk(const unsigned short* __restrict__ Qb,
                                            const unsigned short* __restrict__ Kb,
                                            const unsigned short* __restrict__ QT,
                                            const float* __restrict__ LSE,
                                            unsigned short* __restrict__ DQK) {
    __shared__ unsigned short Qtile[2][64 * 64];
    __shared__ unsigned short Ttile[2][64 * 64];
    __shared__ unsigned short P[4][2048];
    const int tid = threadIdx.x, lane = tid & 63, wv = tid >> 6;
    const int bh = blockIdx.x, mt = blockIdx.y;
    const int mw = mt * 128 + wv * 32;
    const int lr = lane & 15, lg = lane >> 4;
    unsigned short* Pw = &P[wv][0];

    auto stage = [&](int buf, int n0) {
#pragma unroll
        for (int iss = 0; iss < 2; ++iss) {
            int p = iss * 256 + tid;
            int row = p >> 3, c = p & 7, cs = c ^ (row & 7);
            gload_lds16(&Qb[((size_t)(bh << 10) + n0 + row) * 64 + cs * 8],
                        (char*)&Qtile[buf][0] + p * 16);
            gload_lds16(&QT[((size_t)bh * 64 + row) * 1024 + n0 + cs * 8],
                        (char*)&Ttile[buf][0] + p * 16);
        }
    };

    short8v ka[2][2];
#pragma unroll
    for (int rb = 0; rb < 2; ++rb)
#pragma unroll
        for (int kc = 0; kc < 2; ++kc)
            ka[rb][kc] = *(const short8v*)&Kb[((size_t)(bh << 10) + mw + rb * 16 + lr) * 64 + kc * 32 + lg * 8];

    f32x4 dk[2][4];
#pragma unroll
    for (int rb = 0; rb < 2; ++rb)
#pragma unroll
        for (int qb = 0; qb < 4; ++qb) dk[rb][qb] = (f32x4){0.f, 0.f, 0.f, 0.f};

    stage(0, 0);
    __syncthreads();
    int buf = 0;
    for (int ntl = 0; ntl < 16; ++ntl) {
        const int n0 = ntl * 64;
        float lse_c[4];
#pragma unroll
        for (int ct = 0; ct < 4; ++ct)
            lse_c[ct] = LSE[(size_t)(bh << 10) + n0 + ct * 16 + lr];
        if (ntl < 15) stage(buf ^ 1, n0 + 64);
        const char* Qt = (const char*)&Qtile[buf][0];
        const char* Tt = (const char*)&Ttile[buf][0];
#pragma unroll
        for (int ct = 0; ct < 4; ++ct) {
            int brow = ct * 16 + lr;
            short8v bq0 = *(const short8v*)(Qt + brow * 128 + ((lg) ^ (brow & 7)) * 16);
            short8v bq1 = *(const short8v*)(Qt + brow * 128 + ((lg + 4) ^ (brow & 7)) * 16);
#pragma unroll
            for (int rb = 0; rb < 2; ++rb) {
                f32x4 s = {0.f, 0.f, 0.f, 0.f};
                s = __builtin_amdgcn_mfma_f32_16x16x32_bf16(ka[rb][0], bq0, s, 0, 0, 0);
                s = __builtin_amdgcn_mfma_f32_16x16x32_bf16(ka[rb][1], bq1, s, 0, 0, 0);
#pragma unroll
                for (int r = 0; r < 4; ++r) {
                    float p = __expf(s[r] * BETA - lse_c[ct]);
                    int row = rb * 16 + lg * 4 + r;
                    int off = (row * 64 + ct * 16 + lr) ^ ((row & 7) << 3);
                    Pw[off] = f2b(p);
                }
            }
        }
        short8v pa[2][2];
#pragma unroll
        for (int rb = 0; rb < 2; ++rb) {
            int row = rb * 16 + lr;
#pragma unroll
            for (int kc = 0; kc < 2; ++kc) {
                int off = (row * 64 + kc * 32 + lg * 8) ^ ((row & 7) << 3);
                pa[rb][kc] = *(const short8v*)&Pw[off];
            }
        }
#pragma unroll
        for (int qb = 0; qb < 4; ++qb) {
            int brow = qb * 16 + lr;
            short8v b0 = *(const short8v*)(Tt + brow * 128 + ((lg) ^ (brow & 7)) * 16);
            short8v b1 = *(const short8v*)(Tt + brow * 128 + ((lg + 4) ^ (brow & 7)) * 16);
#pragma unroll
            for (int rb = 0; rb < 2; ++rb) {
                dk[rb][qb] = __builtin_amdgcn_mfma_f32_16x16x32_bf16(pa[rb][0], b0, dk[rb][qb], 0, 0, 0);
                dk[rb][qb] = __builtin_amdgcn_mfma_f32_16x16x32_bf16(pa[rb][1], b1, dk[rb][qb], 0, 0, 0);
            }
        }
        __syncthreads();
        buf ^= 1;
    }
    const int b = bh >> 4, h = bh & 15;
#pragma unroll
    for (int rb = 0; rb < 2; ++rb)
#pragma unroll
        for (int qb = 0; qb < 4; ++qb)
#pragma unroll
            for (int r = 0; r < 4; ++r)
                DQK[((size_t)(b << 10) + mw + rb * 16 + lg * 4 + r) * 2048 + 1024 + h * 64 + qb * 16 + lr] = f2b(-dk[rb][qb][r]);
}

// ---------------- K8: finalize energy ----------------
__global__ __launch_bounds__(256) void k_fin(const float* __restrict__ pl,
                                             const float* __restrict__ ph,
                                             float* __restrict__ out) {
    const int tid = threadIdx.x;
    float s1 = 0.f, s2 = 0.f;
    for (int i = tid; i < 2048; i += 256) s1 += pl[i];
    for (int i = tid; i < 1024; i += 256) s2 += ph[i];
#pragma unroll
    for (int off = 32; off; off >>= 1) {
        s1 += __shfl_down(s1, off);
        s2 += __shfl_down(s2, off);
    }
    __shared__ float r1[4], r2[4];
    if ((tid & 63) == 0) { r1[tid >> 6] = s1; r2[tid >> 6] = s2; }
    __syncthreads();
    if (tid == 0) {
        float S1 = r1[0] + r1[1] + r1[2] + r1[3];
        float S2 = r2[0] + r2[1] + r2[2] + r2[3];
        out[(size_t)4194304] = -INV_BETA * S1 - 0.5f * S2;
    }
}

extern "C" void kernel_launch(void* const* d_in, const int* in_sizes, int n_in,
                              void* d_out, int out_size, void* d_ws, size_t ws_size,
                              hipStream_t stream) {
    (void)in_sizes; (void)n_in; (void)out_size; (void)ws_size;
    const float* x    = (const float*)d_in[0];
    const float* Wq   = (const float*)d_in[1];
    const float* Wk   = (const float*)d_in[2];
    const float* Whop = (const float*)d_in[3];
    float* out = (float*)d_out;
    float* ws = (float*)d_ws;

    unsigned short* XB   = (unsigned short*)(ws + OFF_XB);
    unsigned short* WCB  = (unsigned short*)(ws + OFF_WCB);
    unsigned short* WCTB = (unsigned short*)(ws + OFF_WCTB);
    unsigned short* WHB  = (unsigned short*)(ws + OFF_WHB);
    unsigned short* WHTB = (unsigned short*)(ws + OFF_WHTB);
    unsigned short* H    = (unsigned short*)(ws + OFF_H);
    unsigned short* Qb   = (unsigned short*)(ws + OFF_QB);
    unsigned short* Kb   = (unsigned short*)(ws + OFF_KB);
    unsigned short* QT   = (unsigned short*)(ws + OFF_QT);
    unsigned short* KT   = (unsigned short*)(ws + OFF_KT);
    unsigned short* DQK  = (unsigned short*)(ws + OFF_DQK);
    float* LSE = ws + OFF_LSE;
    float* PL  = ws + OFF_PL;
    float* PH  = ws + OFF_PH;

    dim3 blk(256);
    k_castall<<<dim3(10240), blk, 0, stream>>>(x, Wq, Wk, Whop, XB, WCB, WHB);
    k_tall<<<dim3(192, 32), dim3(32, 8), 0, stream>>>(Wq, Wk, Whop, WCTB, WHTB);

    mm_proj<<<dim3(32, 16), blk, 0, stream>>>(XB, WCB, Qb, Kb);
    k_tqk<<<dim3(16, 64, 2), blk, 0, stream>>>(Qb, Kb, QT, KT);
    k_dq<<<dim3(64, 8), blk, 0, stream>>>(Qb, Kb, KT, LSE, PL, DQK);
    k_dk<<<dim3(64, 8), blk, 0, stream>>>(Qb, Kb, QT, LSE, DQK);

    mm_hopfwd<<<dim3(32, 32), blk, 0, stream>>>(XB, WHTB, H, PH);
    mm_hopbwd<<<dim3(32, 16), blk, 0, stream>>>(H, WHB, out);
    mm_gradproj<<<dim3(32, 16), blk, 0, stream>>>(DQK, WCTB, out);
    k_fin<<<dim3(1), blk, 0, stream>>>(PL, PH, out);
}